// Round 23
// baseline (159.077 us; speedup 1.0000x reference)
//
#include <hip/hip_runtime.h>
#include <hip/hip_fp16.h>

#define FIN 128
#define BSH 9                 // 512 nodes per bucket
#define BMASK ((1 << BSH) - 1)
#define CHUNK 8192            // edges per binpass block
#define BCAP 10240            // per-bucket padded region capacity (mean ~8675)

typedef _Float16 half4 __attribute__((ext_vector_type(4)));
typedef _Float16 h2v __attribute__((ext_vector_type(2)));
typedef float f32x4 __attribute__((ext_vector_type(4)));

// ---------------- standalone MFMA dual GEMM (layer 2) ----------------------
template<int K, bool FP32IN>
__global__ __launch_bounds__(256) void gemm_mfma(
    const void* __restrict__ xin, const float* __restrict__ wl,
    const float* __restrict__ wr, __half* __restrict__ outl,
    __half* __restrict__ outr, int n) {
  constexpr int WSTR = K + 4;
  __shared__ _Float16 Wt[128 * WSTR];
  const int tid = threadIdx.x;
  for (int i4 = tid; i4 < K * 16; i4 += 256) {
    const int k = i4 >> 4, c0 = (i4 & 15) << 2;
    const float4 vl = *(const float4*)&wl[k * 64 + c0];
    const float4 vr = *(const float4*)&wr[k * 64 + c0];
    Wt[(c0 + 0) * WSTR + k] = (_Float16)vl.x;
    Wt[(c0 + 1) * WSTR + k] = (_Float16)vl.y;
    Wt[(c0 + 2) * WSTR + k] = (_Float16)vl.z;
    Wt[(c0 + 3) * WSTR + k] = (_Float16)vl.w;
    Wt[(c0 + 64) * WSTR + k] = (_Float16)vr.x;
    Wt[(c0 + 65) * WSTR + k] = (_Float16)vr.y;
    Wt[(c0 + 66) * WSTR + k] = (_Float16)vr.z;
    Wt[(c0 + 67) * WSTR + k] = (_Float16)vr.w;
  }
  __syncthreads();
  const int lane = tid & 63;
  const int wv = tid >> 6;
  const int r0 = blockIdx.x * 64 + wv * 16;
  const int rowc = min(r0 + (lane & 15), n - 1);
  const int kgrp = (lane >> 4) << 2;
  const int col16 = lane & 15;
  f32x4 acc[8];
#pragma unroll
  for (int cf = 0; cf < 8; ++cf) acc[cf] = {0.f, 0.f, 0.f, 0.f};
  for (int ks = 0; ks < K / 16; ++ks) {
    const int kb = ks * 16 + kgrp;
    half4 a;
    if (FP32IN) {
      const float4 av =
          *(const float4*)((const float*)xin + (size_t)rowc * K + kb);
      a = {(_Float16)av.x, (_Float16)av.y, (_Float16)av.z, (_Float16)av.w};
    } else {
      a = *(const half4*)((const __half*)xin + (size_t)rowc * K + kb);
    }
#pragma unroll
    for (int cf = 0; cf < 8; ++cf) {
      const half4 b = *(const half4*)&Wt[(cf * 16 + col16) * WSTR + kb];
      acc[cf] = __builtin_amdgcn_mfma_f32_16x16x16f16(a, b, acc[cf], 0, 0, 0);
    }
  }
  const int crow0 = r0 + ((lane >> 4) << 2);
#pragma unroll
  for (int cf = 0; cf < 8; ++cf) {
    const int c = cf * 16 + col16;
    __half* outp = (c < 64) ? outl : outr;
    const int cc = c & 63;
#pragma unroll
    for (int r = 0; r < 4; ++r) {
      const int rr = crow0 + r;
      if (rr < n) outp[(size_t)rr * 64 + cc] = (__half)acc[cf][r];
    }
  }
}

// ---------------- CSR build: binpass (vectorized int4 edge loads) ----------
__global__ __launch_bounds__(256) void binpass(
    const int* __restrict__ src, const int* __restrict__ dst, int E, int ET,
    int NB, int* __restrict__ gcursor, unsigned* __restrict__ sorted_val) {
  __shared__ unsigned lval[CHUNK];
  __shared__ unsigned short lrank[CHUNK];
  __shared__ unsigned char lb[CHUNK];
  __shared__ int c1[256], base[256];
  const int tid = threadIdx.x;
  c1[tid] = 0;
  __syncthreads();
  const int e0 = blockIdx.x * CHUNK;

#define BPROC(idx_, s_, d_)                                                  \
  {                                                                          \
    const int b_ = (d_) >> BSH;                                              \
    lval[idx_] = (unsigned)(s_) | ((unsigned)((d_) & BMASK) << 17);          \
    lb[idx_] = (unsigned char)b_;                                            \
    lrank[idx_] = (unsigned short)atomicAdd(&c1[b_], 1);                     \
  }

#pragma unroll
  for (int j = 0; j < CHUNK / 1024; ++j) {  // 4 edges per thread per iter
    const int q = tid + 256 * j;
    const int e = e0 + 4 * q;
    if (e + 3 < E) {  // aligned int4 fast path
      const int4 s4 = *(const int4*)&src[e];
      const int4 d4 = *(const int4*)&dst[e];
      BPROC(4 * q + 0, s4.x, d4.x);
      BPROC(4 * q + 1, s4.y, d4.y);
      BPROC(4 * q + 2, s4.z, d4.z);
      BPROC(4 * q + 3, s4.w, d4.w);
    } else {  // boundary + self-loop range
#pragma unroll
      for (int t = 0; t < 4; ++t) {
        const int ee = e + t;
        const int idx = 4 * q + t;
        if (ee < ET) {
          int s, d;
          if (ee < E) {
            s = src[ee];
            d = dst[ee];
          } else {
            s = d = ee - E;  // self loop
          }
          BPROC(idx, s, d);
        } else {
          lb[idx] = 255;
        }
      }
    }
  }
#undef BPROC
  __syncthreads();
  if (tid < NB && c1[tid] > 0)
    base[tid] = tid * BCAP + atomicAdd(&gcursor[tid], c1[tid]);
  __syncthreads();
#pragma unroll
  for (int j = 0; j < CHUNK / 256; ++j) {
    const int idx = tid + 256 * j;
    const int b = lb[idx];
    if (b != 255) sorted_val[base[b] + lrank[idx]] = lval[idx];
  }
}

// ---------------- FUSED: bucket_scatter (blocks < NB) + gemm1 (rest) -------
__global__ __launch_bounds__(256) void scatter_gemm1(
    const int* __restrict__ gcursor, const unsigned* __restrict__ sorted_val,
    int n, int* __restrict__ ssrc, int2* __restrict__ off2,
    const float* __restrict__ x, const float* __restrict__ wl,
    const float* __restrict__ wr, __half* __restrict__ outl,
    __half* __restrict__ outr, int NB,
    const float* __restrict__ att1, const float* __restrict__ att2,
    __half* __restrict__ att1h, __half* __restrict__ att2h) {
  __shared__ __align__(16) char smem[49152];
  const int tid = threadIdx.x;

  if (blockIdx.x == 0 && tid < 64) {  // att fp16 pre-convert (x log2e)
    att1h[tid] = (__half)(att1[tid] * 1.44269504f);
    att2h[tid] = (__half)(att2[tid] * 1.44269504f);
  }

  if (blockIdx.x < (unsigned)NB) {
    // ----- bucket_scatter body -----
    int* cnt = (int*)smem;
    int* sa = cnt + 512;
    int* sb = sa + 512;
    int* cur = sb + 512;
    int* buf = cur + 512;  // [BCAP]
    const int b = blockIdx.x;
    const int node0 = b << BSH;
    const int nn = min(512, n - node0);
    const int rbase = b * BCAP;
    const int rlen = gcursor[b];
    for (int j = tid; j < 512; j += 256) cnt[j] = 0;
    __syncthreads();
    for (int i = tid; i < rlen; i += 256)
      atomicAdd(&cnt[sorted_val[rbase + i] >> 17], 1);
    __syncthreads();
    for (int j = tid; j < 512; j += 256) sa[j] = cnt[j];
    __syncthreads();
    int* pin = sa;
    int* pout = sb;
    for (int off = 1; off < 512; off <<= 1) {  // Hillis-Steele inclusive scan
      for (int j = tid; j < 512; j += 256)
        pout[j] = pin[j] + (j >= off ? pin[j - off] : 0);
      __syncthreads();
      int* t = pin;
      pin = pout;
      pout = t;
    }
    for (int j = tid; j < 512; j += 256) {
      const int excl = pin[j] - cnt[j];
      cur[j] = excl;
      if (j < nn) off2[node0 + j] = make_int2(rbase + excl, rbase + pin[j]);
    }
    __syncthreads();
    if (rlen <= BCAP) {
      for (int i = tid; i < rlen; i += 256) {
        const unsigned v = sorted_val[rbase + i];
        const int p = atomicAdd(&cur[v >> 17], 1);
        buf[p] = (int)(v & 0x1FFFFu);
      }
      __syncthreads();
      for (int i = tid; i < rlen; i += 256) ssrc[rbase + i] = buf[i];
    } else {
      for (int i = tid; i < rlen; i += 256) {
        const unsigned v = sorted_val[rbase + i];
        const int p = atomicAdd(&cur[v >> 17], 1);
        ssrc[rbase + p] = (int)(v & 0x1FFFFu);
      }
    }
  } else {
    // ----- gemm1 body (K=128, fp32 in, fp16 out) -----
    constexpr int K = 128;
    constexpr int WSTR = K + 4;
    _Float16* Wt = (_Float16*)smem;  // 128*132*2 = 33792 B
    for (int i4 = tid; i4 < K * 16; i4 += 256) {
      const int k = i4 >> 4, c0 = (i4 & 15) << 2;
      const float4 vl = *(const float4*)&wl[k * 64 + c0];
      const float4 vr = *(const float4*)&wr[k * 64 + c0];
      Wt[(c0 + 0) * WSTR + k] = (_Float16)vl.x;
      Wt[(c0 + 1) * WSTR + k] = (_Float16)vl.y;
      Wt[(c0 + 2) * WSTR + k] = (_Float16)vl.z;
      Wt[(c0 + 3) * WSTR + k] = (_Float16)vl.w;
      Wt[(c0 + 64) * WSTR + k] = (_Float16)vr.x;
      Wt[(c0 + 65) * WSTR + k] = (_Float16)vr.y;
      Wt[(c0 + 66) * WSTR + k] = (_Float16)vr.z;
      Wt[(c0 + 67) * WSTR + k] = (_Float16)vr.w;
    }
    __syncthreads();
    const int lane = tid & 63;
    const int wv = tid >> 6;
    const int r0 = (blockIdx.x - NB) * 64 + wv * 16;
    const int rowc = min(r0 + (lane & 15), n - 1);
    const int kgrp = (lane >> 4) << 2;
    const int col16 = lane & 15;
    f32x4 acc[8];
#pragma unroll
    for (int cf = 0; cf < 8; ++cf) acc[cf] = {0.f, 0.f, 0.f, 0.f};
    for (int ks = 0; ks < K / 16; ++ks) {
      const int kb = ks * 16 + kgrp;
      const float4 av = *(const float4*)&x[(size_t)rowc * K + kb];
      const half4 a = {(_Float16)av.x, (_Float16)av.y, (_Float16)av.z,
                       (_Float16)av.w};
#pragma unroll
      for (int cf = 0; cf < 8; ++cf) {
        const half4 bb = *(const half4*)&Wt[(cf * 16 + col16) * WSTR + kb];
        acc[cf] = __builtin_amdgcn_mfma_f32_16x16x16f16(a, bb, acc[cf], 0, 0, 0);
      }
    }
    const int crow0 = r0 + ((lane >> 4) << 2);
#pragma unroll
    for (int cf = 0; cf < 8; ++cf) {
      const int c = cf * 16 + col16;
      __half* outp = (c < 64) ? outl : outr;
      const int cc = c & 63;
#pragma unroll
      for (int r = 0; r < 4; ++r) {
        const int rr = crow0 + r;
        if (rr < n) outp[(size_t)rr * 64 + cc] = (__half)acc[cf][r];
      }
    }
  }
}

// ---------------- Node-major attention pass, 16 edges/wave -----------------
// Lane owns ONE full head: grp=lane>>2 (16 edge groups), sl=lane&3 = head,
// channels 16sl..16sl+15 (32 B = 2 float4 loads, 4 lanes x 32 B = 128 B/edge
// coalesced). Logit dot fully in-register (8 fdot2, NO cross-lane ops);
// a=exp2(p) per lane is that head's alpha directly. den reduce: 4 shfl_xor
// over group bits + 1 redistribution shfl. Epilogue transpose via padded
// [16][68] LDS rows (write banks spread by grp*68%32, read conflict-free).
template<bool RELU, typename OT>
__global__ __launch_bounds__(256) void node_pass(
    const int2* __restrict__ off2, const int* __restrict__ ssrc,
    const __half* __restrict__ xl, const __half* __restrict__ xr,
    const __half* __restrict__ atth, const float* __restrict__ bias,
    OT* __restrict__ out, int n) {
  __shared__ float part[4][16][68];
  const int lane = threadIdx.x & 63;
  const int wv = threadIdx.x >> 6;
  const int grp = lane >> 2;  // edge group 0..15
  const int sl = lane & 3;    // head; channels 16sl..16sl+15
  const int d = (blockIdx.x * blockDim.x + threadIdx.x) >> 6;
  if (d >= n) return;
  const int2 oo = off2[d];
  const int beg = oo.x, end = oo.y;  // end > beg (self loop)
  const int deg = end - beg;

  union H16 { float4 f4[2]; h2v h2[8]; uint4 u4[2]; };
  H16 ath;
  ath.u4[0] = *(const uint4*)&atth[16 * sl];
  ath.u4[1] = *(const uint4*)&atth[16 * sl + 8];
  H16 xrv;
  xrv.f4[0] = *(const float4*)&xr[(size_t)d * 64 + 16 * sl];
  xrv.f4[1] = *(const float4*)&xr[(size_t)d * 64 + 16 * sl + 8];

  h2v acch[8] = {{(_Float16)0.f, (_Float16)0.f}, {(_Float16)0.f, (_Float16)0.f},
                 {(_Float16)0.f, (_Float16)0.f}, {(_Float16)0.f, (_Float16)0.f},
                 {(_Float16)0.f, (_Float16)0.f}, {(_Float16)0.f, (_Float16)0.f},
                 {(_Float16)0.f, (_Float16)0.f}, {(_Float16)0.f, (_Float16)0.f}};
  float den = 0.f;

  const unsigned slb = (unsigned)(sl * 32);  // byte offset of channel block
  const int sv = ssrc[min(beg + lane, end - 1)];

#define EDGE_CORE(lo_, hi_)                                                  \
  {                                                                          \
    H16 ul;                                                                  \
    ul.f4[0] = (lo_);                                                        \
    ul.f4[1] = (hi_);                                                        \
    float pa = 0.f, pb = 0.f;                                                \
    _Pragma("unroll") for (int q = 0; q < 4; ++q) {                          \
      const h2v t = ul.h2[q] + xrv.h2[q];                                    \
      const h2v lk = __builtin_elementwise_max(t, t * (_Float16)0.2f);       \
      pa = __builtin_amdgcn_fdot2(lk, ath.h2[q], pa, false);                 \
    }                                                                        \
    _Pragma("unroll") for (int q = 4; q < 8; ++q) {                          \
      const h2v t = ul.h2[q] + xrv.h2[q];                                    \
      const h2v lk = __builtin_elementwise_max(t, t * (_Float16)0.2f);       \
      pb = __builtin_amdgcn_fdot2(lk, ath.h2[q], pb, false);                 \
    }                                                                        \
    const float a = exp2f(pa + pb);                                          \
    const _Float16 ah = (_Float16)a;                                         \
    const h2v aa = {ah, ah};                                                 \
    _Pragma("unroll") for (int q = 0; q < 8; ++q) acch[q] += ul.h2[q] * aa;  \
    den += a;                                                                \
  }

  if (deg <= 64) {
    // -------- fast path: depth-2 pipeline over 16-edge batches --------
#define XLF(base_, lo_, hi_)                                                 \
  {                                                                          \
    const int s_ = __shfl(sv, ((base_) - beg + grp) & 63);                   \
    const unsigned voff_ = (unsigned)s_ * 128u + slb;                        \
    lo_ = *(const float4*)((const char*)xl + voff_);                         \
    hi_ = *(const float4*)((const char*)xl + voff_ + 16);                    \
  }
    float4 a0l, a0h, a1l, a1h, nxl, nxh;
    XLF(beg, a0l, a0h);
    XLF(beg + 16, a1l, a1h);
    int base = beg;
#pragma unroll 2
    for (; base + 16 <= end; base += 16) {  // full batches, no predicate
      XLF(base + 32, nxl, nxh);
      EDGE_CORE(a0l, a0h);
      a0l = a1l;
      a0h = a1h;
      a1l = nxl;
      a1h = nxh;
    }
    if (base < end) {  // single masked tail batch (group-uniform predicate)
      if (base + grp < end) EDGE_CORE(a0l, a0h);
    }
#undef XLF
  } else {
    // -------- slow path (rare at Poisson deg~17) --------
    for (int base = beg; base < end; base += 16) {
      if (base + grp < end) {
        const int s_ = ssrc[base + grp];
        const unsigned voff_ = (unsigned)s_ * 128u + slb;
        const float4 lo = *(const float4*)((const char*)xl + voff_);
        const float4 hi = *(const float4*)((const char*)xl + voff_ + 16);
        EDGE_CORE(lo, hi);
      }
    }
  }
#undef EDGE_CORE

  // ---- epilogue ----
  // den: combine the 16 edge groups (group bits are lane bits 2..5).
#pragma unroll
  for (int m = 4; m <= 32; m <<= 1) den += __shfl_xor(den, m);
  // channel c = lane belongs to head lane>>4, whose den sits on lane (lane>>4)
  // (that lane has grp=0, sl=lane>>4).
  const float den_c = __shfl(den, lane >> 4);

  // acc transpose: lane writes its 16 channels at part[wv][grp][16sl..+15].
  float accf[16];
#pragma unroll
  for (int q = 0; q < 8; ++q) {
    accf[2 * q] = (float)acch[q].x;
    accf[2 * q + 1] = (float)acch[q].y;
  }
  float* pw = &part[wv][grp][16 * sl];
#pragma unroll
  for (int q = 0; q < 4; ++q)
    *(float4*)&pw[4 * q] =
        make_float4(accf[4 * q], accf[4 * q + 1], accf[4 * q + 2],
                    accf[4 * q + 3]);
  float s = 0.f;  // wave-internal dependency: compiler inserts lgkmcnt wait
#pragma unroll
  for (int g = 0; g < 16; ++g) s += part[wv][g][lane];

  float v = s / den_c + bias[lane];
  if (RELU) v = fmaxf(v, 0.f);
  out[(size_t)d * 64 + lane] = (OT)v;
}

extern "C" void kernel_launch(void* const* d_in, const int* in_sizes, int n_in,
                              void* d_out, int out_size, void* d_ws, size_t ws_size,
                              hipStream_t stream) {
  const float* x    = (const float*)d_in[0];
  const int*   ei   = (const int*)d_in[1];
  const float* wl1  = (const float*)d_in[2];
  const float* wr1  = (const float*)d_in[3];
  const float* att1 = (const float*)d_in[4];
  const float* b1   = (const float*)d_in[5];
  const float* wl2  = (const float*)d_in[6];
  const float* wr2  = (const float*)d_in[7];
  const float* att2 = (const float*)d_in[8];
  const float* b2   = (const float*)d_in[9];
  float* out = (float*)d_out;

  const int n = in_sizes[0] / FIN;   // 100000 (< 2^17, required by packing)
  const int E = in_sizes[1] / 2;     // 1600000
  const int ET = E + n;
  const int* src = ei;
  const int* dst = ei + E;
  const int NB = (n + (1 << BSH) - 1) >> BSH;  // 196 (< 255, u8 sentinel)

  __half* A  = (__half*)d_ws;                       // [n*64] fp16
  __half* B  = A + (size_t)n * 64;                  // [n*64] fp16
  __half* Hh = B + (size_t)n * 64;                  // [n*64] fp16 (layer-1 h)
  __half* att1h = Hh + (size_t)n * 64;              // [64]
  __half* att2h = att1h + 64;                       // [64]
  int2* off2 = (int2*)(att2h + 64);                 // [n]
  int* gcursor = (int*)(off2 + n);                  // [256]
  unsigned* sorted_val = (unsigned*)(gcursor + 256);// [NB*BCAP]
  int* ssrc = (int*)(sorted_val + (size_t)NB * BCAP);  // [NB*BCAP]

  const int nbin = (ET + CHUNK - 1) / CHUNK;        // 208
  const int gb = (n + 63) / 64;                     // 1563 gemm blocks
  const int nb = (n * 64 + 255) / 256;              // one wave per node

  // ---- CSR build + layer-1 GEMM (overlapped) ----
  hipMemsetAsync(gcursor, 0, 256 * sizeof(int), stream);
  binpass<<<nbin, 256, 0, stream>>>(src, dst, E, ET, NB, gcursor, sorted_val);
  scatter_gemm1<<<NB + gb, 256, 0, stream>>>(
      gcursor, sorted_val, n, ssrc, off2, x, wl1, wr1, A, B, NB, att1, att2,
      att1h, att2h);

  // ---- layer 1 attention ----
  node_pass<true, __half><<<nb, 256, 0, stream>>>(off2, ssrc, A, B, att1h, b1,
                                                  Hh, n);

  // ---- layer 2 ----
  gemm_mfma<64, false><<<gb, 256, 0, stream>>>(Hh, wl2, wr2, A, B, n);
  node_pass<false, float><<<nb, 256, 0, stream>>>(off2, ssrc, A, B, att2h, b2,
                                                  out, n);
}

// Round 24
// 149.581 us; speedup vs baseline: 1.0635x; 1.0635x over previous
//
#include <hip/hip_runtime.h>
#include <hip/hip_fp16.h>

#define FIN 128
#define BSH 9                 // 512 nodes per bucket
#define BMASK ((1 << BSH) - 1)
#define CHUNK 8192            // edges per binpass block
#define BCAP 10240            // per-bucket padded region capacity (mean ~8675)

typedef _Float16 half4 __attribute__((ext_vector_type(4)));
typedef _Float16 h2v __attribute__((ext_vector_type(2)));
typedef float f32x4 __attribute__((ext_vector_type(4)));

// v_add with DPP quad_perm [1,0,3,2]: xor-1 neighbor add, pure VALU (no DS).
static __device__ __forceinline__ float xor1_add(float p) {
  const int sw = __builtin_amdgcn_mov_dpp(__builtin_bit_cast(int, p), 0xB1,
                                          0xF, 0xF, true);
  return p + __builtin_bit_cast(float, sw);
}

// ---------------- standalone MFMA dual GEMM (layer 2) ----------------------
template<int K, bool FP32IN>
__global__ __launch_bounds__(256) void gemm_mfma(
    const void* __restrict__ xin, const float* __restrict__ wl,
    const float* __restrict__ wr, __half* __restrict__ outl,
    __half* __restrict__ outr, int n) {
  constexpr int WSTR = K + 4;
  __shared__ _Float16 Wt[128 * WSTR];
  const int tid = threadIdx.x;
  for (int i4 = tid; i4 < K * 16; i4 += 256) {
    const int k = i4 >> 4, c0 = (i4 & 15) << 2;
    const float4 vl = *(const float4*)&wl[k * 64 + c0];
    const float4 vr = *(const float4*)&wr[k * 64 + c0];
    Wt[(c0 + 0) * WSTR + k] = (_Float16)vl.x;
    Wt[(c0 + 1) * WSTR + k] = (_Float16)vl.y;
    Wt[(c0 + 2) * WSTR + k] = (_Float16)vl.z;
    Wt[(c0 + 3) * WSTR + k] = (_Float16)vl.w;
    Wt[(c0 + 64) * WSTR + k] = (_Float16)vr.x;
    Wt[(c0 + 65) * WSTR + k] = (_Float16)vr.y;
    Wt[(c0 + 66) * WSTR + k] = (_Float16)vr.z;
    Wt[(c0 + 67) * WSTR + k] = (_Float16)vr.w;
  }
  __syncthreads();
  const int lane = tid & 63;
  const int wv = tid >> 6;
  const int r0 = blockIdx.x * 64 + wv * 16;
  const int rowc = min(r0 + (lane & 15), n - 1);
  const int kgrp = (lane >> 4) << 2;
  const int col16 = lane & 15;
  f32x4 acc[8];
#pragma unroll
  for (int cf = 0; cf < 8; ++cf) acc[cf] = {0.f, 0.f, 0.f, 0.f};
  for (int ks = 0; ks < K / 16; ++ks) {
    const int kb = ks * 16 + kgrp;
    half4 a;
    if (FP32IN) {
      const float4 av =
          *(const float4*)((const float*)xin + (size_t)rowc * K + kb);
      a = {(_Float16)av.x, (_Float16)av.y, (_Float16)av.z, (_Float16)av.w};
    } else {
      a = *(const half4*)((const __half*)xin + (size_t)rowc * K + kb);
    }
#pragma unroll
    for (int cf = 0; cf < 8; ++cf) {
      const half4 b = *(const half4*)&Wt[(cf * 16 + col16) * WSTR + kb];
      acc[cf] = __builtin_amdgcn_mfma_f32_16x16x16f16(a, b, acc[cf], 0, 0, 0);
    }
  }
  const int crow0 = r0 + ((lane >> 4) << 2);
#pragma unroll
  for (int cf = 0; cf < 8; ++cf) {
    const int c = cf * 16 + col16;
    __half* outp = (c < 64) ? outl : outr;
    const int cc = c & 63;
#pragma unroll
    for (int r = 0; r < 4; ++r) {
      const int rr = crow0 + r;
      if (rr < n) outp[(size_t)rr * 64 + cc] = (__half)acc[cf][r];
    }
  }
}

// ---------------- CSR build: binpass (vectorized int4 edge loads) ----------
__global__ __launch_bounds__(256) void binpass(
    const int* __restrict__ src, const int* __restrict__ dst, int E, int ET,
    int NB, int* __restrict__ gcursor, unsigned* __restrict__ sorted_val) {
  __shared__ unsigned lval[CHUNK];
  __shared__ unsigned short lrank[CHUNK];
  __shared__ unsigned char lb[CHUNK];
  __shared__ int c1[256], base[256];
  const int tid = threadIdx.x;
  c1[tid] = 0;
  __syncthreads();
  const int e0 = blockIdx.x * CHUNK;

#define BPROC(idx_, s_, d_)                                                  \
  {                                                                          \
    const int b_ = (d_) >> BSH;                                              \
    lval[idx_] = (unsigned)(s_) | ((unsigned)((d_) & BMASK) << 17);          \
    lb[idx_] = (unsigned char)b_;                                            \
    lrank[idx_] = (unsigned short)atomicAdd(&c1[b_], 1);                     \
  }

#pragma unroll
  for (int j = 0; j < CHUNK / 1024; ++j) {  // 4 edges per thread per iter
    const int q = tid + 256 * j;
    const int e = e0 + 4 * q;
    if (e + 3 < E) {  // aligned int4 fast path
      const int4 s4 = *(const int4*)&src[e];
      const int4 d4 = *(const int4*)&dst[e];
      BPROC(4 * q + 0, s4.x, d4.x);
      BPROC(4 * q + 1, s4.y, d4.y);
      BPROC(4 * q + 2, s4.z, d4.z);
      BPROC(4 * q + 3, s4.w, d4.w);
    } else {  // boundary + self-loop range
#pragma unroll
      for (int t = 0; t < 4; ++t) {
        const int ee = e + t;
        const int idx = 4 * q + t;
        if (ee < ET) {
          int s, d;
          if (ee < E) {
            s = src[ee];
            d = dst[ee];
          } else {
            s = d = ee - E;  // self loop
          }
          BPROC(idx, s, d);
        } else {
          lb[idx] = 255;
        }
      }
    }
  }
#undef BPROC
  __syncthreads();
  if (tid < NB && c1[tid] > 0)
    base[tid] = tid * BCAP + atomicAdd(&gcursor[tid], c1[tid]);
  __syncthreads();
#pragma unroll
  for (int j = 0; j < CHUNK / 256; ++j) {
    const int idx = tid + 256 * j;
    const int b = lb[idx];
    if (b != 255) sorted_val[base[b] + lrank[idx]] = lval[idx];
  }
}

// ---------------- FUSED: bucket_scatter (blocks < NB) + gemm1 (rest) -------
__global__ __launch_bounds__(256) void scatter_gemm1(
    const int* __restrict__ gcursor, const unsigned* __restrict__ sorted_val,
    int n, int* __restrict__ ssrc, int2* __restrict__ off2,
    const float* __restrict__ x, const float* __restrict__ wl,
    const float* __restrict__ wr, __half* __restrict__ outl,
    __half* __restrict__ outr, int NB,
    const float* __restrict__ att1, const float* __restrict__ att2,
    __half* __restrict__ att1h, __half* __restrict__ att2h) {
  __shared__ __align__(16) char smem[49152];
  const int tid = threadIdx.x;

  if (blockIdx.x == 0 && tid < 64) {  // att fp16 pre-convert (x log2e)
    att1h[tid] = (__half)(att1[tid] * 1.44269504f);
    att2h[tid] = (__half)(att2[tid] * 1.44269504f);
  }

  if (blockIdx.x < (unsigned)NB) {
    // ----- bucket_scatter body -----
    int* cnt = (int*)smem;
    int* sa = cnt + 512;
    int* sb = sa + 512;
    int* cur = sb + 512;
    int* buf = cur + 512;  // [BCAP]
    const int b = blockIdx.x;
    const int node0 = b << BSH;
    const int nn = min(512, n - node0);
    const int rbase = b * BCAP;
    const int rlen = gcursor[b];
    for (int j = tid; j < 512; j += 256) cnt[j] = 0;
    __syncthreads();
    for (int i = tid; i < rlen; i += 256)
      atomicAdd(&cnt[sorted_val[rbase + i] >> 17], 1);
    __syncthreads();
    for (int j = tid; j < 512; j += 256) sa[j] = cnt[j];
    __syncthreads();
    int* pin = sa;
    int* pout = sb;
    for (int off = 1; off < 512; off <<= 1) {  // Hillis-Steele inclusive scan
      for (int j = tid; j < 512; j += 256)
        pout[j] = pin[j] + (j >= off ? pin[j - off] : 0);
      __syncthreads();
      int* t = pin;
      pin = pout;
      pout = t;
    }
    for (int j = tid; j < 512; j += 256) {
      const int excl = pin[j] - cnt[j];
      cur[j] = excl;
      if (j < nn) off2[node0 + j] = make_int2(rbase + excl, rbase + pin[j]);
    }
    __syncthreads();
    if (rlen <= BCAP) {
      for (int i = tid; i < rlen; i += 256) {
        const unsigned v = sorted_val[rbase + i];
        const int p = atomicAdd(&cur[v >> 17], 1);
        buf[p] = (int)(v & 0x1FFFFu);
      }
      __syncthreads();
      for (int i = tid; i < rlen; i += 256) ssrc[rbase + i] = buf[i];
    } else {
      for (int i = tid; i < rlen; i += 256) {
        const unsigned v = sorted_val[rbase + i];
        const int p = atomicAdd(&cur[v >> 17], 1);
        ssrc[rbase + p] = (int)(v & 0x1FFFFu);
      }
    }
  } else {
    // ----- gemm1 body (K=128, fp32 in, fp16 out) -----
    constexpr int K = 128;
    constexpr int WSTR = K + 4;
    _Float16* Wt = (_Float16*)smem;  // 128*132*2 = 33792 B
    for (int i4 = tid; i4 < K * 16; i4 += 256) {
      const int k = i4 >> 4, c0 = (i4 & 15) << 2;
      const float4 vl = *(const float4*)&wl[k * 64 + c0];
      const float4 vr = *(const float4*)&wr[k * 64 + c0];
      Wt[(c0 + 0) * WSTR + k] = (_Float16)vl.x;
      Wt[(c0 + 1) * WSTR + k] = (_Float16)vl.y;
      Wt[(c0 + 2) * WSTR + k] = (_Float16)vl.z;
      Wt[(c0 + 3) * WSTR + k] = (_Float16)vl.w;
      Wt[(c0 + 64) * WSTR + k] = (_Float16)vr.x;
      Wt[(c0 + 65) * WSTR + k] = (_Float16)vr.y;
      Wt[(c0 + 66) * WSTR + k] = (_Float16)vr.z;
      Wt[(c0 + 67) * WSTR + k] = (_Float16)vr.w;
    }
    __syncthreads();
    const int lane = tid & 63;
    const int wv = tid >> 6;
    const int r0 = (blockIdx.x - NB) * 64 + wv * 16;
    const int rowc = min(r0 + (lane & 15), n - 1);
    const int kgrp = (lane >> 4) << 2;
    const int col16 = lane & 15;
    f32x4 acc[8];
#pragma unroll
    for (int cf = 0; cf < 8; ++cf) acc[cf] = {0.f, 0.f, 0.f, 0.f};
    for (int ks = 0; ks < K / 16; ++ks) {
      const int kb = ks * 16 + kgrp;
      const float4 av = *(const float4*)&x[(size_t)rowc * K + kb];
      const half4 a = {(_Float16)av.x, (_Float16)av.y, (_Float16)av.z,
                       (_Float16)av.w};
#pragma unroll
      for (int cf = 0; cf < 8; ++cf) {
        const half4 bb = *(const half4*)&Wt[(cf * 16 + col16) * WSTR + kb];
        acc[cf] = __builtin_amdgcn_mfma_f32_16x16x16f16(a, bb, acc[cf], 0, 0, 0);
      }
    }
    const int crow0 = r0 + ((lane >> 4) << 2);
#pragma unroll
    for (int cf = 0; cf < 8; ++cf) {
      const int c = cf * 16 + col16;
      __half* outp = (c < 64) ? outl : outr;
      const int cc = c & 63;
#pragma unroll
      for (int r = 0; r < 4; ++r) {
        const int rr = crow0 + r;
        if (rr < n) outp[(size_t)rr * 64 + cc] = (__half)acc[cf][r];
      }
    }
  }
}

// ---------------- Node-major attention pass, 8 edges/wave, packed fp16 -----
// Empirical optimum (R22 config, 149.4-150.0 us): one wave per node, 8
// edges/wave x 8 ch/lane, 24 VGPR / 66% occupancy. Measured regressions:
// R21 per-wave serial 16-node fusion (-35 us occupancy loss), R23 16-edge
// remap (+6 us: 40 VGPR, 4-way LDS conflicts, 16-edge tail waste).
template<bool RELU, typename OT>
__global__ __launch_bounds__(256) void node_pass(
    const int2* __restrict__ off2, const int* __restrict__ ssrc,
    const __half* __restrict__ xl, const __half* __restrict__ xr,
    const __half* __restrict__ atth, const float* __restrict__ bias,
    OT* __restrict__ out, int n) {
  __shared__ float part[4][8][64];
  const int lane = threadIdx.x & 63;
  const int wv = threadIdx.x >> 6;
  const int grp = lane >> 3;
  const int sl = lane & 7;
  const int d = (blockIdx.x * blockDim.x + threadIdx.x) >> 6;
  if (d >= n) return;
  const int2 oo = off2[d];
  const int beg = oo.x, end = oo.y;  // end > beg (self loop)
  const int deg = end - beg;

  union H8 { float4 f4; h2v h2[4]; uint4 u4; };
  H8 ath;
  ath.u4 = *(const uint4*)&atth[8 * sl];
  H8 xrv;
  xrv.f4 = *(const float4*)&xr[(size_t)d * 64 + 8 * sl];

  h2v acch[4] = {{(_Float16)0.f, (_Float16)0.f},
                 {(_Float16)0.f, (_Float16)0.f},
                 {(_Float16)0.f, (_Float16)0.f},
                 {(_Float16)0.f, (_Float16)0.f}};
  float den = 0.f;

  const unsigned slb = (unsigned)(sl * 16);  // per-lane channel byte offset
  const int sv = ssrc[min(beg + lane, end - 1)];

#define EDGE_CORE(vreg_)                                                     \
  {                                                                          \
    H8 ul;                                                                   \
    ul.f4 = (vreg_);                                                         \
    const h2v t0 = ul.h2[0] + xrv.h2[0];                                     \
    const h2v t1 = ul.h2[1] + xrv.h2[1];                                     \
    const h2v t2 = ul.h2[2] + xrv.h2[2];                                     \
    const h2v t3 = ul.h2[3] + xrv.h2[3];                                     \
    const h2v k0 = __builtin_elementwise_max(t0, t0 * (_Float16)0.2f);       \
    const h2v k1 = __builtin_elementwise_max(t1, t1 * (_Float16)0.2f);       \
    const h2v k2 = __builtin_elementwise_max(t2, t2 * (_Float16)0.2f);       \
    const h2v k3 = __builtin_elementwise_max(t3, t3 * (_Float16)0.2f);       \
    float pa = __builtin_amdgcn_fdot2(k0, ath.h2[0], 0.f, false);            \
    float pb = __builtin_amdgcn_fdot2(k2, ath.h2[2], 0.f, false);            \
    pa = __builtin_amdgcn_fdot2(k1, ath.h2[1], pa, false);                   \
    pb = __builtin_amdgcn_fdot2(k3, ath.h2[3], pb, false);                   \
    const float p = xor1_add(pa + pb);                                       \
    const float a = exp2f(p);                                                \
    const _Float16 ah = (_Float16)a;                                         \
    const h2v aa = {ah, ah};                                                 \
    acch[0] += ul.h2[0] * aa;                                                \
    acch[1] += ul.h2[1] * aa;                                                \
    acch[2] += ul.h2[2] * aa;                                                \
    acch[3] += ul.h2[3] * aa;                                                \
    den += a;                                                                \
  }

  if (deg <= 64) {
    // -------- fast path: depth-3 pipeline --------
#define XLF(base_, dst_)                                                     \
  {                                                                          \
    const int s_ = __shfl(sv, (base_) - beg + grp);                          \
    const unsigned voff_ = (unsigned)s_ * 128u + slb;                        \
    dst_ = *(const float4*)((const char*)xl + voff_);                        \
  }
    float4 a0, a1, a2, nx;
    XLF(beg, a0);
    XLF(beg + 8, a1);
    XLF(beg + 16, a2);
    int base = beg;
#pragma unroll 2
    for (; base + 8 <= end; base += 8) {  // full batches, no predicate
      XLF(base + 24, nx);
      EDGE_CORE(a0);
      a0 = a1;
      a1 = a2;
      a2 = nx;
    }
    if (base < end) {  // single masked tail batch
      if (base + grp < end) EDGE_CORE(a0);
    }
#undef XLF
  } else {
    // -------- slow path (never at this degree distribution) --------
#define XLS(base_, dst_)                                                     \
  {                                                                          \
    const int idx_ = (base_) - beg + grp;                                    \
    int s_ = __shfl(sv, idx_ & 63);                                          \
    if (idx_ >= 64) s_ = ssrc[min((base_) + grp, end - 1)];                  \
    const unsigned voff_ = (unsigned)s_ * 128u + slb;                        \
    dst_ = *(const float4*)((const char*)xl + voff_);                        \
  }
    float4 a0, a1, nx;
    XLS(beg, a0);
    XLS(beg + 8, a1);
    for (int base = beg; base < end; base += 8) {
      XLS(base + 16, nx);
      if (base + grp < end) EDGE_CORE(a0);
      a0 = a1;
      a1 = nx;
    }
#undef XLS
  }
#undef EDGE_CORE

  // ---- epilogue ----
#pragma unroll
  for (int m = 8; m <= 32; m <<= 1) den += __shfl_xor(den, m);
  const float den_c = __shfl(den, (lane >> 4) << 1);

  float acc[8];
#pragma unroll
  for (int q = 0; q < 4; ++q) {
    acc[2 * q] = (float)acch[q].x;
    acc[2 * q + 1] = (float)acch[q].y;
  }
  *(float4*)&part[wv][grp][8 * sl] = make_float4(acc[0], acc[1], acc[2], acc[3]);
  *(float4*)&part[wv][grp][8 * sl + 4] =
      make_float4(acc[4], acc[5], acc[6], acc[7]);
  float s = 0.f;
#pragma unroll
  for (int g = 0; g < 8; ++g) s += part[wv][g][lane];

  float v = s / den_c + bias[lane];
  if (RELU) v = fmaxf(v, 0.f);
  out[(size_t)d * 64 + lane] = (OT)v;
}

extern "C" void kernel_launch(void* const* d_in, const int* in_sizes, int n_in,
                              void* d_out, int out_size, void* d_ws, size_t ws_size,
                              hipStream_t stream) {
  const float* x    = (const float*)d_in[0];
  const int*   ei   = (const int*)d_in[1];
  const float* wl1  = (const float*)d_in[2];
  const float* wr1  = (const float*)d_in[3];
  const float* att1 = (const float*)d_in[4];
  const float* b1   = (const float*)d_in[5];
  const float* wl2  = (const float*)d_in[6];
  const float* wr2  = (const float*)d_in[7];
  const float* att2 = (const float*)d_in[8];
  const float* b2   = (const float*)d_in[9];
  float* out = (float*)d_out;

  const int n = in_sizes[0] / FIN;   // 100000 (< 2^17, required by packing)
  const int E = in_sizes[1] / 2;     // 1600000
  const int ET = E + n;
  const int* src = ei;
  const int* dst = ei + E;
  const int NB = (n + (1 << BSH) - 1) >> BSH;  // 196 (< 255, u8 sentinel)

  __half* A  = (__half*)d_ws;                       // [n*64] fp16
  __half* B  = A + (size_t)n * 64;                  // [n*64] fp16
  __half* Hh = B + (size_t)n * 64;                  // [n*64] fp16 (layer-1 h)
  __half* att1h = Hh + (size_t)n * 64;              // [64]
  __half* att2h = att1h + 64;                       // [64]
  int2* off2 = (int2*)(att2h + 64);                 // [n]
  int* gcursor = (int*)(off2 + n);                  // [256]
  unsigned* sorted_val = (unsigned*)(gcursor + 256);// [NB*BCAP]
  int* ssrc = (int*)(sorted_val + (size_t)NB * BCAP);  // [NB*BCAP]

  const int nbin = (ET + CHUNK - 1) / CHUNK;        // 208
  const int gb = (n + 63) / 64;                     // 1563 gemm blocks
  const int nb = (n * 64 + 255) / 256;              // one wave per node

  // ---- CSR build + layer-1 GEMM (overlapped) ----
  hipMemsetAsync(gcursor, 0, 256 * sizeof(int), stream);
  binpass<<<nbin, 256, 0, stream>>>(src, dst, E, ET, NB, gcursor, sorted_val);
  scatter_gemm1<<<NB + gb, 256, 0, stream>>>(
      gcursor, sorted_val, n, ssrc, off2, x, wl1, wr1, A, B, NB, att1, att2,
      att1h, att2h);

  // ---- layer 1 attention ----
  node_pass<true, __half><<<nb, 256, 0, stream>>>(off2, ssrc, A, B, att1h, b1,
                                                  Hh, n);

  // ---- layer 2 ----
  gemm_mfma<64, false><<<gb, 256, 0, stream>>>(Hh, wl2, wr2, A, B, n);
  node_pass<false, float><<<nb, 256, 0, stream>>>(off2, ssrc, A, B, att2h, b2,
                                                  out, n);
}

// Round 25
// 145.470 us; speedup vs baseline: 1.0935x; 1.0283x over previous
//
#include <hip/hip_runtime.h>
#include <hip/hip_fp16.h>

#define FIN 128
#define BSH 9                 // 512 nodes per bucket
#define BMASK ((1 << BSH) - 1)
#define CHUNK 8192            // edges per binpass block
#define BCAP 10240            // per-bucket padded region capacity (mean ~8675)

typedef _Float16 half4 __attribute__((ext_vector_type(4)));
typedef _Float16 h2v __attribute__((ext_vector_type(2)));
typedef float f32x4 __attribute__((ext_vector_type(4)));

// v_add with DPP quad_perm [1,0,3,2]: xor-1 neighbor add, pure VALU (no DS).
static __device__ __forceinline__ float xor1_add(float p) {
  const int sw = __builtin_amdgcn_mov_dpp(__builtin_bit_cast(int, p), 0xB1,
                                          0xF, 0xF, true);
  return p + __builtin_bit_cast(float, sw);
}

// ---------------- standalone MFMA dual GEMM (layer 2) ----------------------
template<int K, bool FP32IN>
__global__ __launch_bounds__(256) void gemm_mfma(
    const void* __restrict__ xin, const float* __restrict__ wl,
    const float* __restrict__ wr, __half* __restrict__ outl,
    __half* __restrict__ outr, int n) {
  constexpr int WSTR = K + 4;
  __shared__ _Float16 Wt[128 * WSTR];
  const int tid = threadIdx.x;
  for (int i4 = tid; i4 < K * 16; i4 += 256) {
    const int k = i4 >> 4, c0 = (i4 & 15) << 2;
    const float4 vl = *(const float4*)&wl[k * 64 + c0];
    const float4 vr = *(const float4*)&wr[k * 64 + c0];
    Wt[(c0 + 0) * WSTR + k] = (_Float16)vl.x;
    Wt[(c0 + 1) * WSTR + k] = (_Float16)vl.y;
    Wt[(c0 + 2) * WSTR + k] = (_Float16)vl.z;
    Wt[(c0 + 3) * WSTR + k] = (_Float16)vl.w;
    Wt[(c0 + 64) * WSTR + k] = (_Float16)vr.x;
    Wt[(c0 + 65) * WSTR + k] = (_Float16)vr.y;
    Wt[(c0 + 66) * WSTR + k] = (_Float16)vr.z;
    Wt[(c0 + 67) * WSTR + k] = (_Float16)vr.w;
  }
  __syncthreads();
  const int lane = tid & 63;
  const int wv = tid >> 6;
  const int r0 = blockIdx.x * 64 + wv * 16;
  const int rowc = min(r0 + (lane & 15), n - 1);
  const int kgrp = (lane >> 4) << 2;
  const int col16 = lane & 15;
  f32x4 acc[8];
#pragma unroll
  for (int cf = 0; cf < 8; ++cf) acc[cf] = {0.f, 0.f, 0.f, 0.f};
  for (int ks = 0; ks < K / 16; ++ks) {
    const int kb = ks * 16 + kgrp;
    half4 a;
    if (FP32IN) {
      const float4 av =
          *(const float4*)((const float*)xin + (size_t)rowc * K + kb);
      a = {(_Float16)av.x, (_Float16)av.y, (_Float16)av.z, (_Float16)av.w};
    } else {
      a = *(const half4*)((const __half*)xin + (size_t)rowc * K + kb);
    }
#pragma unroll
    for (int cf = 0; cf < 8; ++cf) {
      const half4 b = *(const half4*)&Wt[(cf * 16 + col16) * WSTR + kb];
      acc[cf] = __builtin_amdgcn_mfma_f32_16x16x16f16(a, b, acc[cf], 0, 0, 0);
    }
  }
  const int crow0 = r0 + ((lane >> 4) << 2);
#pragma unroll
  for (int cf = 0; cf < 8; ++cf) {
    const int c = cf * 16 + col16;
    __half* outp = (c < 64) ? outl : outr;
    const int cc = c & 63;
#pragma unroll
    for (int r = 0; r < 4; ++r) {
      const int rr = crow0 + r;
      if (rr < n) outp[(size_t)rr * 64 + cc] = (__half)acc[cf][r];
    }
  }
}

// ---------------- CSR build: binpass (vectorized int4 edge loads) ----------
__global__ __launch_bounds__(256) void binpass(
    const int* __restrict__ src, const int* __restrict__ dst, int E, int ET,
    int NB, int* __restrict__ gcursor, unsigned* __restrict__ sorted_val) {
  __shared__ unsigned lval[CHUNK];
  __shared__ unsigned short lrank[CHUNK];
  __shared__ unsigned char lb[CHUNK];
  __shared__ int c1[256], base[256];
  const int tid = threadIdx.x;
  c1[tid] = 0;
  __syncthreads();
  const int e0 = blockIdx.x * CHUNK;

#define BPROC(idx_, s_, d_)                                                  \
  {                                                                          \
    const int b_ = (d_) >> BSH;                                              \
    lval[idx_] = (unsigned)(s_) | ((unsigned)((d_) & BMASK) << 17);          \
    lb[idx_] = (unsigned char)b_;                                            \
    lrank[idx_] = (unsigned short)atomicAdd(&c1[b_], 1);                     \
  }

#pragma unroll
  for (int j = 0; j < CHUNK / 1024; ++j) {  // 4 edges per thread per iter
    const int q = tid + 256 * j;
    const int e = e0 + 4 * q;
    if (e + 3 < E) {  // aligned int4 fast path
      const int4 s4 = *(const int4*)&src[e];
      const int4 d4 = *(const int4*)&dst[e];
      BPROC(4 * q + 0, s4.x, d4.x);
      BPROC(4 * q + 1, s4.y, d4.y);
      BPROC(4 * q + 2, s4.z, d4.z);
      BPROC(4 * q + 3, s4.w, d4.w);
    } else {  // boundary + self-loop range
#pragma unroll
      for (int t = 0; t < 4; ++t) {
        const int ee = e + t;
        const int idx = 4 * q + t;
        if (ee < ET) {
          int s, d;
          if (ee < E) {
            s = src[ee];
            d = dst[ee];
          } else {
            s = d = ee - E;  // self loop
          }
          BPROC(idx, s, d);
        } else {
          lb[idx] = 255;
        }
      }
    }
  }
#undef BPROC
  __syncthreads();
  if (tid < NB && c1[tid] > 0)
    base[tid] = tid * BCAP + atomicAdd(&gcursor[tid], c1[tid]);
  __syncthreads();
#pragma unroll
  for (int j = 0; j < CHUNK / 256; ++j) {
    const int idx = tid + 256 * j;
    const int b = lb[idx];
    if (b != 255) sorted_val[base[b] + lrank[idx]] = lval[idx];
  }
}

// ---------------- FUSED: bucket_scatter (blocks < NB) + gemm1 (rest) -------
__global__ __launch_bounds__(256) void scatter_gemm1(
    const int* __restrict__ gcursor, const unsigned* __restrict__ sorted_val,
    int n, int* __restrict__ ssrc, int2* __restrict__ off2,
    const float* __restrict__ x, const float* __restrict__ wl,
    const float* __restrict__ wr, __half* __restrict__ outl,
    __half* __restrict__ outr, int NB,
    const float* __restrict__ att1, const float* __restrict__ att2,
    __half* __restrict__ att1h, __half* __restrict__ att2h) {
  __shared__ __align__(16) char smem[49152];
  const int tid = threadIdx.x;

  if (blockIdx.x == 0 && tid < 64) {  // att fp16 pre-convert (x log2e)
    att1h[tid] = (__half)(att1[tid] * 1.44269504f);
    att2h[tid] = (__half)(att2[tid] * 1.44269504f);
  }

  if (blockIdx.x < (unsigned)NB) {
    // ----- bucket_scatter body -----
    int* cnt = (int*)smem;
    int* sa = cnt + 512;
    int* sb = sa + 512;
    int* cur = sb + 512;
    int* buf = cur + 512;  // [BCAP]
    const int b = blockIdx.x;
    const int node0 = b << BSH;
    const int nn = min(512, n - node0);
    const int rbase = b * BCAP;
    const int rlen = gcursor[b];
    for (int j = tid; j < 512; j += 256) cnt[j] = 0;
    __syncthreads();
    for (int i = tid; i < rlen; i += 256)
      atomicAdd(&cnt[sorted_val[rbase + i] >> 17], 1);
    __syncthreads();
    for (int j = tid; j < 512; j += 256) sa[j] = cnt[j];
    __syncthreads();
    int* pin = sa;
    int* pout = sb;
    for (int off = 1; off < 512; off <<= 1) {  // Hillis-Steele inclusive scan
      for (int j = tid; j < 512; j += 256)
        pout[j] = pin[j] + (j >= off ? pin[j - off] : 0);
      __syncthreads();
      int* t = pin;
      pin = pout;
      pout = t;
    }
    for (int j = tid; j < 512; j += 256) {
      const int excl = pin[j] - cnt[j];
      cur[j] = excl;
      if (j < nn) off2[node0 + j] = make_int2(rbase + excl, rbase + pin[j]);
    }
    __syncthreads();
    if (rlen <= BCAP) {
      for (int i = tid; i < rlen; i += 256) {
        const unsigned v = sorted_val[rbase + i];
        const int p = atomicAdd(&cur[v >> 17], 1);
        buf[p] = (int)(v & 0x1FFFFu);
      }
      __syncthreads();
      for (int i = tid; i < rlen; i += 256) ssrc[rbase + i] = buf[i];
    } else {
      for (int i = tid; i < rlen; i += 256) {
        const unsigned v = sorted_val[rbase + i];
        const int p = atomicAdd(&cur[v >> 17], 1);
        ssrc[rbase + p] = (int)(v & 0x1FFFFu);
      }
    }
  } else {
    // ----- gemm1 body (K=128, fp32 in, fp16 out) -----
    constexpr int K = 128;
    constexpr int WSTR = K + 4;
    _Float16* Wt = (_Float16*)smem;  // 128*132*2 = 33792 B
    for (int i4 = tid; i4 < K * 16; i4 += 256) {
      const int k = i4 >> 4, c0 = (i4 & 15) << 2;
      const float4 vl = *(const float4*)&wl[k * 64 + c0];
      const float4 vr = *(const float4*)&wr[k * 64 + c0];
      Wt[(c0 + 0) * WSTR + k] = (_Float16)vl.x;
      Wt[(c0 + 1) * WSTR + k] = (_Float16)vl.y;
      Wt[(c0 + 2) * WSTR + k] = (_Float16)vl.z;
      Wt[(c0 + 3) * WSTR + k] = (_Float16)vl.w;
      Wt[(c0 + 64) * WSTR + k] = (_Float16)vr.x;
      Wt[(c0 + 65) * WSTR + k] = (_Float16)vr.y;
      Wt[(c0 + 66) * WSTR + k] = (_Float16)vr.z;
      Wt[(c0 + 67) * WSTR + k] = (_Float16)vr.w;
    }
    __syncthreads();
    const int lane = tid & 63;
    const int wv = tid >> 6;
    const int r0 = (blockIdx.x - NB) * 64 + wv * 16;
    const int rowc = min(r0 + (lane & 15), n - 1);
    const int kgrp = (lane >> 4) << 2;
    const int col16 = lane & 15;
    f32x4 acc[8];
#pragma unroll
    for (int cf = 0; cf < 8; ++cf) acc[cf] = {0.f, 0.f, 0.f, 0.f};
    for (int ks = 0; ks < K / 16; ++ks) {
      const int kb = ks * 16 + kgrp;
      const float4 av = *(const float4*)&x[(size_t)rowc * K + kb];
      const half4 a = {(_Float16)av.x, (_Float16)av.y, (_Float16)av.z,
                       (_Float16)av.w};
#pragma unroll
      for (int cf = 0; cf < 8; ++cf) {
        const half4 bb = *(const half4*)&Wt[(cf * 16 + col16) * WSTR + kb];
        acc[cf] = __builtin_amdgcn_mfma_f32_16x16x16f16(a, bb, acc[cf], 0, 0, 0);
      }
    }
    const int crow0 = r0 + ((lane >> 4) << 2);
#pragma unroll
    for (int cf = 0; cf < 8; ++cf) {
      const int c = cf * 16 + col16;
      __half* outp = (c < 64) ? outl : outr;
      const int cc = c & 63;
#pragma unroll
      for (int r = 0; r < 4; ++r) {
        const int rr = crow0 + r;
        if (rr < n) outp[(size_t)rr * 64 + cc] = (__half)acc[cf][r];
      }
    }
  }
}

// ---------------- Node-major attention pass, 8 edges/wave, packed fp16 -----
// R17 form restored (measured 41.0-41.2 us vs 43.1-43.8 for the R18+ SADDR/
// split-tree variant): 64-bit xlp addressing, single fdot2 chain, depth-2
// pipeline, packed fp16 accumulation, DPP xor1, exp2, LDS-transpose epilogue.
template<bool RELU, typename OT>
__global__ __launch_bounds__(256) void node_pass(
    const int2* __restrict__ off2, const int* __restrict__ ssrc,
    const __half* __restrict__ xl, const __half* __restrict__ xr,
    const __half* __restrict__ atth, const float* __restrict__ bias,
    OT* __restrict__ out, int n) {
  __shared__ float part[4][8][64];
  const int lane = threadIdx.x & 63;
  const int wv = threadIdx.x >> 6;
  const int grp = lane >> 3;
  const int sl = lane & 7;
  const int d = (blockIdx.x * blockDim.x + threadIdx.x) >> 6;
  if (d >= n) return;
  const int2 oo = off2[d];
  const int beg = oo.x, end = oo.y;  // end > beg (self loop)
  const int deg = end - beg;

  union H8 { float4 f4; h2v h2[4]; uint4 u4; };
  H8 ath;
  ath.u4 = *(const uint4*)&atth[8 * sl];
  H8 xrv;
  xrv.f4 = *(const float4*)&xr[(size_t)d * 64 + 8 * sl];

  h2v acch[4] = {{(_Float16)0.f, (_Float16)0.f},
                 {(_Float16)0.f, (_Float16)0.f},
                 {(_Float16)0.f, (_Float16)0.f},
                 {(_Float16)0.f, (_Float16)0.f}};
  float den = 0.f;

  const __half* xlp = xl + 8 * sl;  // per-lane channel base
  const int sv = ssrc[min(beg + lane, end - 1)];

#define EDGE_CORE(vreg_)                                                     \
  {                                                                          \
    H8 ul;                                                                   \
    ul.f4 = (vreg_);                                                         \
    float p = 0.f;                                                           \
    _Pragma("unroll") for (int q = 0; q < 4; ++q) {                          \
      const h2v t = ul.h2[q] + xrv.h2[q];                                    \
      const h2v lk = __builtin_elementwise_max(t, t * (_Float16)0.2f);       \
      p = __builtin_amdgcn_fdot2(lk, ath.h2[q], p, false);                   \
    }                                                                        \
    p = xor1_add(p);                                                         \
    const float a = exp2f(p);                                                \
    const _Float16 ah = (_Float16)a;                                         \
    const h2v aa = {ah, ah};                                                 \
    acch[0] += ul.h2[0] * aa;                                                \
    acch[1] += ul.h2[1] * aa;                                                \
    acch[2] += ul.h2[2] * aa;                                                \
    acch[3] += ul.h2[3] * aa;                                                \
    den += a;                                                                \
  }

  if (deg <= 64) {
    // -------- fast path: depth-2 pipeline --------
#define XLF(base_, dst_)                                                     \
  {                                                                          \
    const int s_ = __shfl(sv, (base_) - beg + grp);                          \
    dst_ = *(const float4*)&xlp[(size_t)s_ * 64];                            \
  }
    float4 a0, a1, nx;
    XLF(beg, a0);
    XLF(beg + 8, a1);
    int base = beg;
#pragma unroll 2
    for (; base + 8 <= end; base += 8) {  // full batches, no predicate
      XLF(base + 16, nx);
      EDGE_CORE(a0);
      a0 = a1;
      a1 = nx;
    }
    if (base < end) {  // single masked tail batch
      if (base + grp < end) EDGE_CORE(a0);
    }
#undef XLF
  } else {
    // -------- slow path (never at this degree distribution) --------
#define XLS(base_, dst_)                                                     \
  {                                                                          \
    const int idx_ = (base_) - beg + grp;                                    \
    int s_ = __shfl(sv, idx_ & 63);                                          \
    if (idx_ >= 64) s_ = ssrc[min((base_) + grp, end - 1)];                  \
    dst_ = *(const float4*)&xlp[(size_t)s_ * 64];                            \
  }
    float4 a0, a1, nx;
    XLS(beg, a0);
    XLS(beg + 8, a1);
    for (int base = beg; base < end; base += 8) {
      XLS(base + 16, nx);
      if (base + grp < end) EDGE_CORE(a0);
      a0 = a1;
      a1 = nx;
    }
#undef XLS
  }
#undef EDGE_CORE

  // ---- epilogue ----
#pragma unroll
  for (int m = 8; m <= 32; m <<= 1) den += __shfl_xor(den, m);
  const float den_c = __shfl(den, (lane >> 4) << 1);

  float acc[8];
#pragma unroll
  for (int q = 0; q < 4; ++q) {
    acc[2 * q] = (float)acch[q].x;
    acc[2 * q + 1] = (float)acch[q].y;
  }
  *(float4*)&part[wv][grp][8 * sl] = make_float4(acc[0], acc[1], acc[2], acc[3]);
  *(float4*)&part[wv][grp][8 * sl + 4] =
      make_float4(acc[4], acc[5], acc[6], acc[7]);
  float s = 0.f;
#pragma unroll
  for (int g = 0; g < 8; ++g) s += part[wv][g][lane];

  float v = s / den_c + bias[lane];
  if (RELU) v = fmaxf(v, 0.f);
  out[(size_t)d * 64 + lane] = (OT)v;
}

extern "C" void kernel_launch(void* const* d_in, const int* in_sizes, int n_in,
                              void* d_out, int out_size, void* d_ws, size_t ws_size,
                              hipStream_t stream) {
  const float* x    = (const float*)d_in[0];
  const int*   ei   = (const int*)d_in[1];
  const float* wl1  = (const float*)d_in[2];
  const float* wr1  = (const float*)d_in[3];
  const float* att1 = (const float*)d_in[4];
  const float* b1   = (const float*)d_in[5];
  const float* wl2  = (const float*)d_in[6];
  const float* wr2  = (const float*)d_in[7];
  const float* att2 = (const float*)d_in[8];
  const float* b2   = (const float*)d_in[9];
  float* out = (float*)d_out;

  const int n = in_sizes[0] / FIN;   // 100000 (< 2^17, required by packing)
  const int E = in_sizes[1] / 2;     // 1600000
  const int ET = E + n;
  const int* src = ei;
  const int* dst = ei + E;
  const int NB = (n + (1 << BSH) - 1) >> BSH;  // 196 (< 255, u8 sentinel)

  __half* A  = (__half*)d_ws;                       // [n*64] fp16
  __half* B  = A + (size_t)n * 64;                  // [n*64] fp16
  __half* Hh = B + (size_t)n * 64;                  // [n*64] fp16 (layer-1 h)
  __half* att1h = Hh + (size_t)n * 64;              // [64]
  __half* att2h = att1h + 64;                       // [64]
  int2* off2 = (int2*)(att2h + 64);                 // [n]
  int* gcursor = (int*)(off2 + n);                  // [256]
  unsigned* sorted_val = (unsigned*)(gcursor + 256);// [NB*BCAP]
  int* ssrc = (int*)(sorted_val + (size_t)NB * BCAP);  // [NB*BCAP]

  const int nbin = (ET + CHUNK - 1) / CHUNK;        // 208
  const int gb = (n + 63) / 64;                     // 1563 gemm blocks
  const int nb = (n * 64 + 255) / 256;              // one wave per node

  // ---- CSR build + layer-1 GEMM (overlapped) ----
  hipMemsetAsync(gcursor, 0, 256 * sizeof(int), stream);
  binpass<<<nbin, 256, 0, stream>>>(src, dst, E, ET, NB, gcursor, sorted_val);
  scatter_gemm1<<<NB + gb, 256, 0, stream>>>(
      gcursor, sorted_val, n, ssrc, off2, x, wl1, wr1, A, B, NB, att1, att2,
      att1h, att2h);

  // ---- layer 1 attention ----
  node_pass<true, __half><<<nb, 256, 0, stream>>>(off2, ssrc, A, B, att1h, b1,
                                                  Hh, n);

  // ---- layer 2 ----
  gemm_mfma<64, false><<<gb, 256, 0, stream>>>(Hh, wl2, wr2, A, B, n);
  node_pass<false, float><<<nb, 256, 0, stream>>>(off2, ssrc, A, B, att2h, b2,
                                                  out, n);
}